// Round 5
// baseline (249.296 us; speedup 1.0000x reference)
//
#include <hip/hip_runtime.h>

#define Bc 1024
#define Tc 512
#define Ic 64
#define Hc 32
#define LOG2E2 2.8853900817779268f   // 2*log2(e): tanh(a) = 1 - 2/(2^(a*LOG2E2)+1)

// xt transpose tile: [2 buf][4 batch][32 h][24 t-pitch] bf16 (16 used, pad->48B rows)
#define XT_ROW 24
#define XT_BAT (Hc * XT_ROW)       // 768
#define XT_BUF (4 * XT_BAT)        // 3072

typedef __bf16 bf16x8 __attribute__((ext_vector_type(8)));
typedef __bf16 bf16x4 __attribute__((ext_vector_type(4)));
typedef float  f32x4  __attribute__((ext_vector_type(4)));
typedef _Float16 half2v __attribute__((ext_vector_type(2)));

__device__ inline bf16x8 to_bf16x8(float4 u0, float4 u1) {
    bf16x8 t;
    t[0] = (__bf16)u0.x; t[1] = (__bf16)u0.y; t[2] = (__bf16)u0.z; t[3] = (__bf16)u0.w;
    t[4] = (__bf16)u1.x; t[5] = (__bf16)u1.y; t[6] = (__bf16)u1.z; t[7] = (__bf16)u1.w;
    return t;
}
__device__ inline bf16x8 to_bf16x8s(float4 u0, float4 u1, float s) {
    bf16x8 t;
    t[0] = (__bf16)(u0.x*s); t[1] = (__bf16)(u0.y*s); t[2] = (__bf16)(u0.z*s); t[3] = (__bf16)(u0.w*s);
    t[4] = (__bf16)(u1.x*s); t[5] = (__bf16)(u1.y*s); t[6] = (__bf16)(u1.z*s); t[7] = (__bf16)(u1.w*s);
    return t;
}

// ---------------------------------------------------------------------------
// R10 (resubmit; R4 bench was a container-acquisition failure, same as R1):
// depth-1 gather + 4 batches/wave.
//  - 64 lanes = 4 batches x 16 lanes (batch g = lane>>4). Each lane owns two
//    adjacent h (2m, 2m+1); state = one dword of 2xf16 via v_cvt_pkrtz.
//  - gather: g_k = row_ror:k(c), k=1..15, ALL depth-1 from c (R9's doubling
//    tree was depth-4 of dependent cross-lane movs -- the measured 280-cyc
//    stall). No PLSWAP/cndmask/pack on the chain at all.
//  - each g_k is an (r_2j, r_2j+1) pair -> v_dot2_f32_f16 against per-lane
//    pre-permuted f16 weight pairs (permutation discovered by running the
//    identical RORD network on packed integer indices -- direction-proof).
//  - full-T xq LDS replaced by a 12KB double-buffered 16-t transpose tile
//    (TILE_MFMA writes 2 blocks ahead, xvals read 1 block ahead).
// 256 blocks x 1 wave; latency-bound regime, occupancy irrelevant.
// ---------------------------------------------------------------------------

// DPP row-rotate-right by N within 16-lane rows (all lanes valid)
#define RORD(dst, src, N)                                                     \
    dst = (unsigned)__builtin_amdgcn_mov_dpp((int)(src), 0x120 + (N), 0xF, 0xF, false);

#if __has_builtin(__builtin_amdgcn_fdot2)
#define FDOT(g, W, a)                                                         \
    __builtin_amdgcn_fdot2(__builtin_bit_cast(half2v, (unsigned)(g)), (W), (a), false)
#else
__device__ inline float fdot2_emul(unsigned g, half2v w, float a) {
    half2v v = __builtin_bit_cast(half2v, g);
    a = fmaf((float)v[0], (float)w[0], a);
    return fmaf((float)v[1], (float)w[1], a);
}
#define FDOT(g, W, a) fdot2_emul((g), (W), (a))
#endif

#define STEP(xv0, xv1, uu)                                                    \
    {                                                                         \
        unsigned g1, g2, g3, g4, g5, g6, g7, g8, g9, g10, g11, g12, g13, g14, g15; \
        RORD(g1, c, 1)   RORD(g2, c, 2)   RORD(g3, c, 3)   RORD(g4, c, 4)     \
        RORD(g5, c, 5)   RORD(g6, c, 6)   RORD(g7, c, 7)   RORD(g8, c, 8)     \
        RORD(g9, c, 9)   RORD(g10, c, 10) RORD(g11, c, 11) RORD(g12, c, 12)   \
        RORD(g13, c, 13) RORD(g14, c, 14) RORD(g15, c, 15)                    \
        float a00 = (xv0) + biasc0, a01 = 0.f, a02 = 0.f, a03 = 0.f;          \
        float a10 = (xv1) + biasc1, a11 = 0.f, a12 = 0.f, a13 = 0.f;          \
        a00 = FDOT(c,   W0_0,  a00);  a10 = FDOT(c,   W1_0,  a10);            \
        a01 = FDOT(g1,  W0_1,  a01);  a11 = FDOT(g1,  W1_1,  a11);            \
        a02 = FDOT(g2,  W0_2,  a02);  a12 = FDOT(g2,  W1_2,  a12);            \
        a03 = FDOT(g3,  W0_3,  a03);  a13 = FDOT(g3,  W1_3,  a13);            \
        a00 = FDOT(g4,  W0_4,  a00);  a10 = FDOT(g4,  W1_4,  a10);            \
        a01 = FDOT(g5,  W0_5,  a01);  a11 = FDOT(g5,  W1_5,  a11);            \
        a02 = FDOT(g6,  W0_6,  a02);  a12 = FDOT(g6,  W1_6,  a12);            \
        a03 = FDOT(g7,  W0_7,  a03);  a13 = FDOT(g7,  W1_7,  a13);            \
        a00 = FDOT(g8,  W0_8,  a00);  a10 = FDOT(g8,  W1_8,  a10);            \
        a01 = FDOT(g9,  W0_9,  a01);  a11 = FDOT(g9,  W1_9,  a11);            \
        a02 = FDOT(g10, W0_10, a02);  a12 = FDOT(g10, W1_10, a12);            \
        a03 = FDOT(g11, W0_11, a03);  a13 = FDOT(g11, W1_11, a13);            \
        a00 = FDOT(g12, W0_12, a00);  a10 = FDOT(g12, W1_12, a10);            \
        a01 = FDOT(g13, W0_13, a01);  a11 = FDOT(g13, W1_13, a11);            \
        a02 = FDOT(g14, W0_14, a02);  a12 = FDOT(g14, W1_14, a12);            \
        a03 = FDOT(g15, W0_15, a03);  a13 = FDOT(g15, W1_15, a13);            \
        const float A0 = (a00 + a01) + (a02 + a03);                           \
        const float A1 = (a10 + a11) + (a12 + a13);                           \
        const float p0_ = __builtin_amdgcn_exp2f(A0);                         \
        const float p1_ = __builtin_amdgcn_exp2f(A1);                         \
        rr0 = __builtin_amdgcn_rcpf(p0_ + 1.0f);                              \
        rr1 = __builtin_amdgcn_rcpf(p1_ + 1.0f);                              \
        c = __builtin_bit_cast(unsigned, __builtin_amdgcn_cvt_pkrtz(rr0, rr1)); \
        pbuf[uu][g][m2] = fmaf(rr0, w2o0, fmaf(rr1, w2o1, wos));              \
    }

// bf16x8 -> two float4 (widening, exact)
#define CVT8(dlo, dhi, src)                                                   \
    dlo.x = (float)(src)[0]; dlo.y = (float)(src)[1];                         \
    dlo.z = (float)(src)[2]; dlo.w = (float)(src)[3];                         \
    dhi.x = (float)(src)[4]; dhi.y = (float)(src)[5];                         \
    dhi.z = (float)(src)[6]; dhi.w = (float)(src)[7];

// phase-1 tile: global loads -> regs
#define TILE_LOAD(Xn, bb, lt)                                                 \
    do {                                                                      \
        const float* xp_ =                                                    \
            x + ((size_t)(b0 + (bb)) * Tc + (lt) * 16 + m2) * Ic + q * 8;     \
        Xn##0 = ((const float4*)xp_)[0];                                      \
        Xn##1 = ((const float4*)xp_)[1];                                      \
        Xn##2 = ((const float4*)(xp_ + 32))[0];                               \
        Xn##3 = ((const float4*)(xp_ + 32))[1];                               \
    } while (0)

// phase-1 tile: MFMA + bias + bf16 pack + LDS store into xt tile `tp`
// (R7-verified D layout: col=lane&15 -> h, row=q*4+reg -> t-in-tile)
#define TILE_MFMA(Xn, tp)                                                     \
    do {                                                                      \
        const bf16x8 A0_ = to_bf16x8(Xn##0, Xn##1);                           \
        const bf16x8 A1_ = to_bf16x8(Xn##2, Xn##3);                           \
        f32x4 ac0 = {0.f, 0.f, 0.f, 0.f};                                     \
        f32x4 ac1 = {0.f, 0.f, 0.f, 0.f};                                     \
        ac0 = __builtin_amdgcn_mfma_f32_16x16x32_bf16(A0_, Bf[0][0], ac0, 0, 0, 0); \
        ac0 = __builtin_amdgcn_mfma_f32_16x16x32_bf16(A1_, Bf[0][1], ac0, 0, 0, 0); \
        ac1 = __builtin_amdgcn_mfma_f32_16x16x32_bf16(A0_, Bf[1][0], ac1, 0, 0, 0); \
        ac1 = __builtin_amdgcn_mfma_f32_16x16x32_bf16(A1_, Bf[1][1], ac1, 0, 0, 0); \
        bf16x4 p0_, p1_;                                                      \
        p0_[0] = (__bf16)(ac0[0] + bias0); p0_[1] = (__bf16)(ac0[1] + bias0); \
        p0_[2] = (__bf16)(ac0[2] + bias0); p0_[3] = (__bf16)(ac0[3] + bias0); \
        p1_[0] = (__bf16)(ac1[0] + bias1); p1_[1] = (__bf16)(ac1[1] + bias1); \
        p1_[2] = (__bf16)(ac1[2] + bias1); p1_[3] = (__bf16)(ac1[3] + bias1); \
        *(bf16x4*)&(tp)[m2 * XT_ROW + q * 4]        = p0_;                    \
        *(bf16x4*)&(tp)[(m2 + 16) * XT_ROW + q * 4] = p1_;                    \
    } while (0)

__global__ __launch_bounds__(64, 1) void fused_rnn_kernel(
    const float* __restrict__ x, const float* __restrict__ Wih,
    const float* __restrict__ bih, const float* __restrict__ h0,
    const float* __restrict__ Whh, const float* __restrict__ bhh,
    const float* __restrict__ Wout, const float* __restrict__ bout,
    float* __restrict__ out)
{
    __shared__ __bf16 xt[2 * XT_BUF];     // 12288 B transpose tiles
    __shared__ float  pbuf[16][4][20];    // 5120 B  (t-slot, batch, lane-col pad 20)

    const int lane = threadIdx.x;
    const int m2   = lane & 15;   // lane-in-group / MFMA A-row
    const int q    = lane >> 4;   // MFMA K-quad == batch-in-block g
    const int g    = q;
    const int b0   = blockIdx.x * 4;
    const int hh0  = 2 * m2, hh1 = 2 * m2 + 1;

    // ---- init: Wih fragments (pre-scaled by LOG2E2) ----
    bf16x8 Bf[2][2];
#pragma unroll
    for (int nh = 0; nh < 2; ++nh)
#pragma unroll
        for (int kh = 0; kh < 2; ++kh) {
            const float* wp = Wih + (m2 + 16 * nh) * Ic + q * 8 + kh * 32;
            Bf[nh][kh] = to_bf16x8s(((const float4*)wp)[0],
                                    ((const float4*)wp)[1], LOG2E2);
        }
    const float bias0 = bih[m2] * LOG2E2;
    const float bias1 = bih[m2 + 16] * LOG2E2;

    // ---- index simulation: run the gather network on packed h-indices -----
    unsigned s0 = (unsigned)hh0 | ((unsigned)hh1 << 16);
    unsigned s1, s2, s3, s4, s5, s6, s7, s8, s9, s10, s11, s12, s13, s14, s15;
    RORD(s1, s0, 1)   RORD(s2, s0, 2)   RORD(s3, s0, 3)   RORD(s4, s0, 4)
    RORD(s5, s0, 5)   RORD(s6, s0, 6)   RORD(s7, s0, 7)   RORD(s8, s0, 8)
    RORD(s9, s0, 9)   RORD(s10, s0, 10) RORD(s11, s0, 11) RORD(s12, s0, 12)
    RORD(s13, s0, 13) RORD(s14, s0, 14) RORD(s15, s0, 15)

    // ---- recurrent weights: per-lane permuted f16 pairs, scaled by cw -----
    const float cw = -2.0f * LOG2E2;
    const float* wr0 = Whh + hh0 * Hc;
    const float* wr1 = Whh + hh1 * Hc;
#define MKW2(W0k, W1k, sk)                                                    \
    half2v W0k, W1k;                                                          \
    {                                                                         \
        const unsigned jl_ = (sk) & 0xFFFFu, jh_ = (sk) >> 16;                \
        W0k[0] = (_Float16)(wr0[jl_] * cw); W0k[1] = (_Float16)(wr0[jh_] * cw); \
        W1k[0] = (_Float16)(wr1[jl_] * cw); W1k[1] = (_Float16)(wr1[jh_] * cw); \
    }
    MKW2(W0_0,  W1_0,  s0)   MKW2(W0_1,  W1_1,  s1)
    MKW2(W0_2,  W1_2,  s2)   MKW2(W0_3,  W1_3,  s3)
    MKW2(W0_4,  W1_4,  s4)   MKW2(W0_5,  W1_5,  s5)
    MKW2(W0_6,  W1_6,  s6)   MKW2(W0_7,  W1_7,  s7)
    MKW2(W0_8,  W1_8,  s8)   MKW2(W0_9,  W1_9,  s9)
    MKW2(W0_10, W1_10, s10)  MKW2(W0_11, W1_11, s11)
    MKW2(W0_12, W1_12, s12)  MKW2(W0_13, W1_13, s13)
    MKW2(W0_14, W1_14, s14)  MKW2(W0_15, W1_15, s15)
#undef MKW2

    // bias' = (bhh + rowsum(Whh)) * LOG2E2, per owned h
    float rs0 = 0.f, rs1 = 0.f;
#pragma unroll
    for (int j = 0; j < Hc; ++j) { rs0 += wr0[j]; rs1 += wr1[j]; }
    const float biasc0 = (bhh[hh0] + rs0) * LOG2E2;
    const float biasc1 = (bhh[hh1] + rs1) * LOG2E2;
    const float wo0 = Wout[hh0], wo1 = Wout[hh1];
    const float w2o0 = -2.0f * wo0, w2o1 = -2.0f * wo1;
    const float wos  = wo0 + wo1;
    const float bo   = bout[0];

    // initial state r = (1 - h)/2, packed
    float rr0 = fmaf(-0.5f, h0[(size_t)(b0 + g) * Hc + hh0], 0.5f);
    float rr1 = fmaf(-0.5f, h0[(size_t)(b0 + g) * Hc + hh1], 0.5f);
    unsigned c = __builtin_bit_cast(unsigned, __builtin_amdgcn_cvt_pkrtz(rr0, rr1));
    float* orow = out + (size_t)(b0 + g) * Tc;

    // ---- prologue: tiles for blocks 0,1 into buf0,buf1; loads for block 2 -
    float4 Xa0, Xa1, Xa2, Xa3, Xb0, Xb1, Xb2, Xb3,
           Xc0, Xc1, Xc2, Xc3, Xd0, Xd1, Xd2, Xd3;
    TILE_LOAD(Xa, 0, 0); TILE_LOAD(Xb, 1, 0); TILE_LOAD(Xc, 2, 0); TILE_LOAD(Xd, 3, 0);
    {
        __bf16* tp = xt;  // buf0
        TILE_MFMA(Xa, tp + 0 * XT_BAT); TILE_MFMA(Xb, tp + 1 * XT_BAT);
        TILE_MFMA(Xc, tp + 2 * XT_BAT); TILE_MFMA(Xd, tp + 3 * XT_BAT);
    }
    TILE_LOAD(Xa, 0, 1); TILE_LOAD(Xb, 1, 1); TILE_LOAD(Xc, 2, 1); TILE_LOAD(Xd, 3, 1);
    {
        __bf16* tp = xt + XT_BUF;  // buf1
        TILE_MFMA(Xa, tp + 0 * XT_BAT); TILE_MFMA(Xb, tp + 1 * XT_BAT);
        TILE_MFMA(Xc, tp + 2 * XT_BAT); TILE_MFMA(Xd, tp + 3 * XT_BAT);
    }
    TILE_LOAD(Xa, 0, 2); TILE_LOAD(Xb, 1, 2); TILE_LOAD(Xc, 2, 2); TILE_LOAD(Xd, 3, 2);
    __syncthreads();   // single wave; drains LDS writes before reads

    // per-lane xt read base: own two h-rows of own batch
    const __bf16* xr0base = xt + g * XT_BAT + hh0 * XT_ROW;
    const __bf16* xr1base = xt + g * XT_BAT + hh1 * XT_ROW;

    // xvals for block 0
    bf16x8 na0 = *(const bf16x8*)(xr0base), na1 = *(const bf16x8*)(xr0base + 8);
    bf16x8 nb0 = *(const bf16x8*)(xr1base), nb1 = *(const bf16x8*)(xr1base + 8);
    float4 qa0, qa1, qa2, qa3, qb0, qb1, qb2, qb3;
    CVT8(qa0, qa1, na0) CVT8(qa2, qa3, na1)
    CVT8(qb0, qb1, nb0) CVT8(qb2, qb3, nb1)

#pragma unroll 1
    for (int tb = 0; tb < Tc / 16; ++tb) {
        // prefetch xvals for block tb+1 (written during tb-1); clamp at end
        const int tbn = (tb + 1 < Tc / 16) ? tb + 1 : tb;
        const __bf16* xr0 = xr0base + (tbn & 1) * XT_BUF;
        const __bf16* xr1 = xr1base + (tbn & 1) * XT_BUF;
        na0 = *(const bf16x8*)(xr0); na1 = *(const bf16x8*)(xr0 + 8);
        nb0 = *(const bf16x8*)(xr1); nb1 = *(const bf16x8*)(xr1 + 8);

        // fused phase-1: tiles for tb+2 (regs from tb-1), loads for tb+3
        if (tb + 2 < Tc / 16) {
            __bf16* tp = xt + (tb & 1) * XT_BUF;
            TILE_MFMA(Xa, tp + 0 * XT_BAT); TILE_MFMA(Xb, tp + 1 * XT_BAT);
            TILE_MFMA(Xc, tp + 2 * XT_BAT); TILE_MFMA(Xd, tp + 3 * XT_BAT);
        }
        if (tb + 3 < Tc / 16) {
            TILE_LOAD(Xa, 0, tb + 3); TILE_LOAD(Xb, 1, tb + 3);
            TILE_LOAD(Xc, 2, tb + 3); TILE_LOAD(Xd, 3, tb + 3);
        }

        STEP(qa0.x, qb0.x, 0)  STEP(qa0.y, qb0.y, 1)
        STEP(qa0.z, qb0.z, 2)  STEP(qa0.w, qb0.w, 3)
        STEP(qa1.x, qb1.x, 4)  STEP(qa1.y, qb1.y, 5)
        STEP(qa1.z, qb1.z, 6)  STEP(qa1.w, qb1.w, 7)
        STEP(qa2.x, qb2.x, 8)  STEP(qa2.y, qb2.y, 9)
        STEP(qa2.z, qb2.z, 10) STEP(qa2.w, qb2.w, 11)
        STEP(qa3.x, qb3.x, 12) STEP(qa3.y, qb3.y, 13)
        STEP(qa3.z, qb3.z, 14) STEP(qa3.w, qb3.w, 15)

        __builtin_amdgcn_wave_barrier();

        // all 64 lanes reduce: lane (g, m2) sums t-slot m2 of batch g
        {
            const float4* pr = (const float4*)&pbuf[m2][g][0];
            const float4 s0_ = pr[0], s1_ = pr[1], s2_ = pr[2], s3_ = pr[3];
            const float s =
                (((s0_.x + s0_.y) + (s0_.z + s0_.w)) +
                 ((s1_.x + s1_.y) + (s1_.z + s1_.w))) +
                (((s2_.x + s2_.y) + (s2_.z + s2_.w)) +
                 ((s3_.x + s3_.y) + (s3_.z + s3_.w)));
            orow[tb * 16 + m2] = s + bo;
        }
        __builtin_amdgcn_wave_barrier();

        CVT8(qa0, qa1, na0) CVT8(qa2, qa3, na1)
        CVT8(qb0, qb1, nb0) CVT8(qb2, qb3, nb1)
    }

    // h_last: [1, B, H] appended after outs [B, T, 1]; h = 1 - 2r
    float2* hl = (float2*)(out + (size_t)Bc * Tc + (size_t)(b0 + g) * Hc + hh0);
    float2 hv;
    hv.x = fmaf(-2.0f, rr0, 1.0f);
    hv.y = fmaf(-2.0f, rr1, 1.0f);
    *hl = hv;
}

extern "C" void kernel_launch(void* const* d_in, const int* in_sizes, int n_in,
                              void* d_out, int out_size, void* d_ws, size_t ws_size,
                              hipStream_t stream) {
    const float* x    = (const float*)d_in[0];
    const float* h0   = (const float*)d_in[1];
    const float* Wih  = (const float*)d_in[2];
    const float* bih  = (const float*)d_in[3];
    const float* Whh  = (const float*)d_in[4];
    const float* bhh  = (const float*)d_in[5];
    const float* Wout = (const float*)d_in[6];
    const float* bout = (const float*)d_in[7];
    float* out = (float*)d_out;

    fused_rnn_kernel<<<Bc / 4, 64, 0, stream>>>(x, Wih, bih, h0, Whh, bhh,
                                                Wout, bout, out);
}

// Round 6
// 225.209 us; speedup vs baseline: 1.1070x; 1.1070x over previous
//
#include <hip/hip_runtime.h>

#define Bc 1024
#define Tc 512
#define Ic 64
#define Hc 32
#define L2E2 2.8853900817779268f   // 2*log2(e): tanh(a) = 1 - 2/(2^(a*L2E2)+1)

// xt transpose tile: [2 buf][32 h][24 t-pitch] bf16 (16 used; 48B rows)
#define XT_ROW 24
#define XT_BUF (Hc * XT_ROW)       // 768 elems per buffer

typedef __bf16 bf16x8 __attribute__((ext_vector_type(8)));
typedef __bf16 bf16x4 __attribute__((ext_vector_type(4)));
typedef float  f32x4  __attribute__((ext_vector_type(4)));
typedef _Float16 half2v __attribute__((ext_vector_type(2)));
typedef unsigned uint2v __attribute__((ext_vector_type(2)));

__device__ inline bf16x8 to_bf16x8(float4 u0, float4 u1) {
    bf16x8 t;
    t[0] = (__bf16)u0.x; t[1] = (__bf16)u0.y; t[2] = (__bf16)u0.z; t[3] = (__bf16)u0.w;
    t[4] = (__bf16)u1.x; t[5] = (__bf16)u1.y; t[6] = (__bf16)u1.z; t[7] = (__bf16)u1.w;
    return t;
}
__device__ inline bf16x8 to_bf16x8s(float4 u0, float4 u1, float s) {
    bf16x8 t;
    t[0] = (__bf16)(u0.x*s); t[1] = (__bf16)(u0.y*s); t[2] = (__bf16)(u0.z*s); t[3] = (__bf16)(u0.w*s);
    t[4] = (__bf16)(u1.x*s); t[5] = (__bf16)(u1.y*s); t[6] = (__bf16)(u1.z*s); t[7] = (__bf16)(u1.w*s);
    return t;
}

// ---------------------------------------------------------------------------
// R11: minimum-instruction scan step. Empirical law from R8/R9/R10:
// time ~ 3.5 x per-wave issue-cycles (single-wave dependent-issue bound) --
// so cut instruction COUNT, not gather depth.
//  - 1 batch/block (1024 blocks, 4 waves/CU = 1/SIMD). Lane (r,m), r=lane>>4:
//    owns output h = 2m + (r&1); rows r and r^2 do complementary dot halves.
//  - state c = pkrtz(r_2m, r_2m+1), identical in all 4 rows (pack via
//    permlane16_swap + cndmask makes this automatic).
//  - gather (9 insts): c8=ror8(c); base=(lane<32)?c:c8; 7x row_ror from base.
//    Weight permutation discovered by running the identical network on
//    packed integer h-indices at init (direction-proof).
//  - half-dot: 8 fdot2, 2 chains; addends fold xv (tile pre-scaled by 0.5)
//    and biasc/2 -> zero per-step bias instructions.
//  - combine: {o0,o1}=permlane32_swap(Ah,Ah); A=o0+o1 -- correct for any
//    swap direction since {o0,o1}={own,partner}.
//  - fused MFMA x-proj pipeline (R10 schedule, 1 batch): tiles 2 ahead,
//    loads 3 ahead, xvals 1 ahead; 5.4KB LDS.
// ---------------------------------------------------------------------------

// DPP row-rotate-right by N within 16-lane rows (all lanes valid)
#define RORD(dst, src, N)                                                     \
    dst = (unsigned)__builtin_amdgcn_mov_dpp((int)(src), 0x120 + (N), 0xF, 0xF, false);

#if __has_builtin(__builtin_amdgcn_permlane16_swap)
#define PLSWAP(A, B)                                                          \
    { uint2v _t = __builtin_amdgcn_permlane16_swap((A), (B), false, false);   \
      (A) = _t[0]; (B) = _t[1]; }
#else
#define PLSWAP(A, B)                                                          \
    asm("s_nop 1\n\tv_permlane16_swap_b32 %0, %1" : "+v"(A), "+v"(B));
#endif

#if __has_builtin(__builtin_amdgcn_permlane32_swap)
#define P32SWAP(A, B)                                                         \
    { uint2v _t = __builtin_amdgcn_permlane32_swap((A), (B), false, false);   \
      (A) = _t[0]; (B) = _t[1]; }
#else
#define P32SWAP(A, B)                                                         \
    asm("s_nop 1\n\tv_permlane32_swap_b32 %0, %1" : "+v"(A), "+v"(B));
#endif

#if __has_builtin(__builtin_amdgcn_fdot2)
#define FDOT(g, W, a)                                                         \
    __builtin_amdgcn_fdot2(__builtin_bit_cast(half2v, (unsigned)(g)), (W), (a), false)
#else
__device__ inline float fdot2_emul(unsigned g, half2v w, float a) {
    half2v v = __builtin_bit_cast(half2v, g);
    a = fmaf((float)v[0], (float)w[0], a);
    return fmaf((float)v[1], (float)w[1], a);
}
#define FDOT(g, W, a) fdot2_emul((g), (W), (a))
#endif

#define STEP(xv, uu)                                                          \
    {                                                                         \
        unsigned c8;                                                          \
        RORD(c8, c, 8)                                                        \
        const unsigned bse = rlo ? c : c8;                                    \
        unsigned g1, g2, g3, g4, g5, g6, g7;                                  \
        RORD(g1, bse, 1) RORD(g2, bse, 2) RORD(g3, bse, 3) RORD(g4, bse, 4)   \
        RORD(g5, bse, 5) RORD(g6, bse, 6) RORD(g7, bse, 7)                    \
        float a0 = FDOT(bse, W0, (xv));                                       \
        float a1 = FDOT(g1,  W1, bch);                                        \
        a0 = FDOT(g2, W2, a0);  a1 = FDOT(g3, W3, a1);                        \
        a0 = FDOT(g4, W4, a0);  a1 = FDOT(g5, W5, a1);                        \
        a0 = FDOT(g6, W6, a0);  a1 = FDOT(g7, W7, a1);                        \
        const float Ah = a0 + a1;                                             \
        unsigned sa = __builtin_bit_cast(unsigned, Ah), sb2 = sa;             \
        P32SWAP(sa, sb2)                                                      \
        const float A = __builtin_bit_cast(float, sa) +                       \
                        __builtin_bit_cast(float, sb2);                       \
        const float p_ = __builtin_amdgcn_exp2f(A);                           \
        rr = __builtin_amdgcn_rcpf(p_ + 1.0f);                                \
        pbuf[uu][hh] = fmaf(rr, w2o, wo);                                     \
        unsigned P0 = __builtin_bit_cast(unsigned, rr), P1 = P0;              \
        PLSWAP(P0, P1)                                                        \
        const float rrp = __builtin_bit_cast(float, psel ? P0 : P1);          \
        const float ev = rodd ? rrp : rr;                                     \
        const float od = rodd ? rr : rrp;                                     \
        c = __builtin_bit_cast(unsigned, __builtin_amdgcn_cvt_pkrtz(ev, od)); \
    }

// bf16x8 -> two float4 (widening, exact)
#define CVT8(dlo, dhi, src)                                                   \
    dlo.x = (float)(src)[0]; dlo.y = (float)(src)[1];                         \
    dlo.z = (float)(src)[2]; dlo.w = (float)(src)[3];                         \
    dhi.x = (float)(src)[4]; dhi.y = (float)(src)[5];                         \
    dhi.z = (float)(src)[6]; dhi.w = (float)(src)[7];

// phase-1 tile: global loads -> regs (own batch b)
#define TILE_LOAD(lt)                                                         \
    do {                                                                      \
        const float* xp_ = x + ((size_t)b * Tc + (lt) * 16 + m2) * Ic + r * 8;\
        Xa0 = ((const float4*)xp_)[0];                                        \
        Xa1 = ((const float4*)xp_)[1];                                        \
        Xa2 = ((const float4*)(xp_ + 32))[0];                                 \
        Xa3 = ((const float4*)(xp_ + 32))[1];                                 \
    } while (0)

// phase-1 tile: MFMA + bias + bf16 pack + LDS store into xt buffer `tp`
// (R7-verified D layout: col=lane&15 -> h, row=r*4+reg -> t-in-tile)
#define TILE_MFMA(tp)                                                         \
    do {                                                                      \
        const bf16x8 A0_ = to_bf16x8(Xa0, Xa1);                               \
        const bf16x8 A1_ = to_bf16x8(Xa2, Xa3);                               \
        f32x4 ac0 = {0.f, 0.f, 0.f, 0.f};                                     \
        f32x4 ac1 = {0.f, 0.f, 0.f, 0.f};                                     \
        ac0 = __builtin_amdgcn_mfma_f32_16x16x32_bf16(A0_, Bf[0][0], ac0, 0, 0, 0); \
        ac0 = __builtin_amdgcn_mfma_f32_16x16x32_bf16(A1_, Bf[0][1], ac0, 0, 0, 0); \
        ac1 = __builtin_amdgcn_mfma_f32_16x16x32_bf16(A0_, Bf[1][0], ac1, 0, 0, 0); \
        ac1 = __builtin_amdgcn_mfma_f32_16x16x32_bf16(A1_, Bf[1][1], ac1, 0, 0, 0); \
        bf16x4 p0_, p1_;                                                      \
        p0_[0] = (__bf16)(ac0[0] + bias0); p0_[1] = (__bf16)(ac0[1] + bias0); \
        p0_[2] = (__bf16)(ac0[2] + bias0); p0_[3] = (__bf16)(ac0[3] + bias0); \
        p1_[0] = (__bf16)(ac1[0] + bias1); p1_[1] = (__bf16)(ac1[1] + bias1); \
        p1_[2] = (__bf16)(ac1[2] + bias1); p1_[3] = (__bf16)(ac1[3] + bias1); \
        *(bf16x4*)&(tp)[m2 * XT_ROW + r * 4]        = p0_;                    \
        *(bf16x4*)&(tp)[(m2 + 16) * XT_ROW + r * 4] = p1_;                    \
    } while (0)

__global__ __launch_bounds__(64, 1) void fused_rnn_kernel(
    const float* __restrict__ x, const float* __restrict__ Wih,
    const float* __restrict__ bih, const float* __restrict__ h0,
    const float* __restrict__ Whh, const float* __restrict__ bhh,
    const float* __restrict__ Wout, const float* __restrict__ bout,
    float* __restrict__ out)
{
    __shared__ __bf16 xt[2 * XT_BUF];   // 3072 B
    __shared__ float  pbuf[16][36];     // 2304 B   (t-slot, h with pad)

    const int lane = threadIdx.x;
    const int m2   = lane & 15;          // lane-in-row / MFMA A-row (t)
    const int r    = lane >> 4;          // row 0..3  (MFMA K-chunk)
    const bool rlo  = (lane < 32);       // dot lo-half rows
    const bool rodd = (r & 1);           // odd-h rows
    const int  hh   = 2 * m2 + (r & 1);  // owned output h
    const int  b    = blockIdx.x;        // one batch per block

    // ---- init: Wih fragments, pre-scaled by 0.5*L2E2 (added by both halves)
    const float shalf = 0.5f * L2E2;
    bf16x8 Bf[2][2];
#pragma unroll
    for (int nh = 0; nh < 2; ++nh)
#pragma unroll
        for (int kh = 0; kh < 2; ++kh) {
            const float* wp = Wih + (m2 + 16 * nh) * Ic + r * 8 + kh * 32;
            Bf[nh][kh] = to_bf16x8s(((const float4*)wp)[0],
                                    ((const float4*)wp)[1], shalf);
        }
    const float bias0 = bih[m2] * shalf;
    const float bias1 = bih[m2 + 16] * shalf;

    // ---- psel discovery for permlane16_swap (R9-proven) -------------------
    bool psel;
    {
        unsigned d0 = (unsigned)lane, d1 = (unsigned)lane;
        PLSWAP(d0, d1)
        psel = (d0 == (unsigned)(lane ^ 16));
    }

    // ---- index simulation: identical network on packed h-indices ----------
    unsigned s0p = (unsigned)(2 * m2) | ((unsigned)(2 * m2 + 1) << 16);
    unsigned s8p;
    RORD(s8p, s0p, 8)
    const unsigned sbp = rlo ? s0p : s8p;
    unsigned sk1, sk2, sk3, sk4, sk5, sk6, sk7;
    RORD(sk1, sbp, 1) RORD(sk2, sbp, 2) RORD(sk3, sbp, 3) RORD(sk4, sbp, 4)
    RORD(sk5, sbp, 5) RORD(sk6, sbp, 6) RORD(sk7, sbp, 7)

    // ---- per-lane permuted f16 weight pairs (own h row, scaled -2*L2E2) ---
    const float cw = -2.0f * L2E2;
    const float* wrh = Whh + hh * Hc;
#define MKW(Wk, sk)                                                           \
    half2v Wk;                                                                \
    {                                                                         \
        const unsigned jl_ = (sk) & 0xFFFFu, jh_ = (sk) >> 16;                \
        Wk[0] = (_Float16)(wrh[jl_] * cw);                                    \
        Wk[1] = (_Float16)(wrh[jh_] * cw);                                    \
    }
    MKW(W0, sbp) MKW(W1, sk1) MKW(W2, sk2) MKW(W3, sk3)
    MKW(W4, sk4) MKW(W5, sk5) MKW(W6, sk6) MKW(W7, sk7)
#undef MKW

    // biasc/2 = (bhh + rowsum(Whh))*L2E2/2 (each half adds it once)
    float rs = 0.f;
#pragma unroll
    for (int j = 0; j < Hc; ++j) rs += wrh[j];
    const float bch = (bhh[hh] + rs) * shalf;
    const float wo  = Wout[hh];
    const float w2o = -2.0f * wo;
    const float bo  = bout[0];

    // initial state r = (1 - h)/2; pack own pair (no cross-lane needed)
    const float h0e = h0[(size_t)b * Hc + 2 * m2];
    const float h0o = h0[(size_t)b * Hc + 2 * m2 + 1];
    const float re0 = fmaf(-0.5f, h0e, 0.5f);
    const float ro0 = fmaf(-0.5f, h0o, 0.5f);
    unsigned c = __builtin_bit_cast(unsigned, __builtin_amdgcn_cvt_pkrtz(re0, ro0));
    float rr = rodd ? ro0 : re0;
    float* orow = out + (size_t)b * Tc;

    // ---- prologue: tiles 0,1 -> buf0,buf1; stage loads for tile 2 ---------
    float4 Xa0, Xa1, Xa2, Xa3;
    TILE_LOAD(0);
    TILE_MFMA(xt);
    TILE_LOAD(1);
    TILE_MFMA(xt + XT_BUF);
    TILE_LOAD(2);
    __syncthreads();   // single wave; drain LDS writes before reads

    const __bf16* xrbase = xt + hh * XT_ROW;

    // xvals for tile 0
    bf16x8 na0 = *(const bf16x8*)(xrbase), na1 = *(const bf16x8*)(xrbase + 8);
    float4 qa0, qa1, qa2, qa3;
    CVT8(qa0, qa1, na0) CVT8(qa2, qa3, na1)

#pragma unroll 1
    for (int tb = 0; tb < Tc / 16; ++tb) {
        // prefetch xvals for tile tb+1 (written during tb-1); clamp at end
        const int tbn = (tb + 1 < Tc / 16) ? tb + 1 : tb;
        const __bf16* xr = xrbase + (tbn & 1) * XT_BUF;
        na0 = *(const bf16x8*)(xr); na1 = *(const bf16x8*)(xr + 8);

        // fused phase-1: tile tb+2 (regs loaded at tb-1), loads for tb+3
        if (tb + 2 < Tc / 16) { TILE_MFMA(xt + (tb & 1) * XT_BUF); }
        if (tb + 3 < Tc / 16) { TILE_LOAD(tb + 3); }

        STEP(qa0.x, 0)  STEP(qa0.y, 1)  STEP(qa0.z, 2)  STEP(qa0.w, 3)
        STEP(qa1.x, 4)  STEP(qa1.y, 5)  STEP(qa1.z, 6)  STEP(qa1.w, 7)
        STEP(qa2.x, 8)  STEP(qa2.y, 9)  STEP(qa2.z, 10) STEP(qa2.w, 11)
        STEP(qa3.x, 12) STEP(qa3.y, 13) STEP(qa3.z, 14) STEP(qa3.w, 15)

        __builtin_amdgcn_wave_barrier();

        // reduce: lane m (<16) sums the 32 h-partials of t-slot m
        if (lane < 16) {
            const float4* pr = (const float4*)&pbuf[lane][0];
            const float4 s0_ = pr[0], s1_ = pr[1], s2_ = pr[2], s3_ = pr[3];
            const float4 s4_ = pr[4], s5_ = pr[5], s6_ = pr[6], s7_ = pr[7];
            const float s =
                ((((s0_.x + s0_.y) + (s0_.z + s0_.w)) +
                  ((s1_.x + s1_.y) + (s1_.z + s1_.w))) +
                 (((s2_.x + s2_.y) + (s2_.z + s2_.w)) +
                  ((s3_.x + s3_.y) + (s3_.z + s3_.w)))) +
                ((((s4_.x + s4_.y) + (s4_.z + s4_.w)) +
                  ((s5_.x + s5_.y) + (s5_.z + s5_.w))) +
                 (((s6_.x + s6_.y) + (s6_.z + s6_.w)) +
                  ((s7_.x + s7_.y) + (s7_.z + s7_.w))));
            orow[tb * 16 + lane] = s + bo;
        }
        __builtin_amdgcn_wave_barrier();

        CVT8(qa0, qa1, na0) CVT8(qa2, qa3, na1)
    }

    // h_last: [1, B, H] appended after outs [B, T, 1]; h = 1 - 2r
    // (two lanes per h write the identical value -- benign)
    out[(size_t)Bc * Tc + (size_t)b * Hc + hh] = fmaf(-2.0f, rr, 1.0f);
}

extern "C" void kernel_launch(void* const* d_in, const int* in_sizes, int n_in,
                              void* d_out, int out_size, void* d_ws, size_t ws_size,
                              hipStream_t stream) {
    const float* x    = (const float*)d_in[0];
    const float* h0   = (const float*)d_in[1];
    const float* Wih  = (const float*)d_in[2];
    const float* bih  = (const float*)d_in[3];
    const float* Whh  = (const float*)d_in[4];
    const float* bhh  = (const float*)d_in[5];
    const float* Wout = (const float*)d_in[6];
    const float* bout = (const float*)d_in[7];
    float* out = (float*)d_out;

    fused_rnn_kernel<<<Bc, 64, 0, stream>>>(x, Wih, bih, h0, Whh, bhh,
                                            Wout, bout, out);
}